// Round 5
// baseline (386.822 us; speedup 1.0000x reference)
//
#include <hip/hip_runtime.h>

#define DEVINL __device__ __forceinline__

DEVINL float leaky(float v) { return v >= 0.f ? v : 0.2f * v; }

// ---------------------------------------------------------------------------
// Precompute per-level head projection vectors:
// w_out[level][2][h][c]; w_src[h][c] = sum_e lin[h*16+e][c]*asrc[h][e]
// ---------------------------------------------------------------------------
__global__ void wprep_kernel(const float* __restrict__ lin,   // (6,64,64)
                             const float* __restrict__ asrc,  // (6,4,16)
                             const float* __restrict__ adst,  // (6,4,16)
                             float* __restrict__ w_out) {     // (6,2,4,64)
    int idx = blockIdx.x * blockDim.x + threadIdx.x;
    if (idx >= 6 * 4 * 64) return;
    int c = idx & 63;
    int h = (idx >> 6) & 3;
    int k = idx >> 8;
    const float* L = lin + k * 64 * 64;
    float s1 = 0.f, s2 = 0.f;
    for (int e = 0; e < 16; ++e) {
        float w = L[(h * 16 + e) * 64 + c];
        s1 += w * asrc[(k * 4 + h) * 16 + e];
        s2 += w * adst[(k * 4 + h) * 16 + e];
    }
    w_out[(k * 2 + 0) * 256 + h * 64 + c] = s1;
    w_out[(k * 2 + 1) * 256 + h * 64 + c] = s2;
}

// ---------------------------------------------------------------------------
// Transpose pool weights once (same as round 4).
// ---------------------------------------------------------------------------
__global__ void wtrans_kernel(const float* __restrict__ s0, const float* __restrict__ s1,
                              const float* __restrict__ t0, const float* __restrict__ t1,
                              const float* __restrict__ s0w2, const float* __restrict__ s1w2,
                              const float* __restrict__ t0w2, const float* __restrict__ t1w2,
                              float* __restrict__ o) {
    int idx = blockIdx.x * 256 + threadIdx.x;
    if (idx < 16384) {
        int m = idx >> 12, r = idx & 4095, c = r >> 6, d = r & 63;
        const float* src = (m == 0) ? s0 : (m == 1) ? s1 : (m == 2) ? t0 : t1;
        o[idx] = src[d * 64 + c];
    } else if (idx < 16384 + 768) {
        int j = idx - 16384, c = j / 12, k = j - 12 * c;
        o[idx] = s0w2[k * 64 + c];
    } else if (idx < 17152 + 512) {
        int j = idx - 17152, c = j >> 3, k = j & 7;
        o[idx] = (k < 5) ? s1w2[k * 64 + c] : 0.f;
    } else if (idx < 17664 + 2048) {
        int j = idx - 17664, c = j >> 5, k = j & 31;
        o[idx] = t0w2[k * 64 + c];
    } else if (idx < 19712 + 768) {
        int j = idx - 19712, c = j / 12, k = j - 12 * c;
        o[idx] = t1w2[k * 64 + c];
    }
}

// ---------------------------------------------------------------------------
// Transposes: src (B=64, C=64, T=64, J=25)
// ---------------------------------------------------------------------------
__global__ void xs_kernel(const float* __restrict__ src, float* __restrict__ xs) {
    int g = blockIdx.x;             // b*64 + t
    int b = g >> 6, t = g & 63;
    __shared__ float tile[64][26];  // [c][j]
    const float* sp = src + b * 102400 + t * 25;
    for (int idx = threadIdx.x; idx < 64 * 25; idx += blockDim.x) {
        int c = idx / 25, j = idx - c * 25;
        tile[c][j] = sp[c * 1600 + j];
    }
    __syncthreads();
    float* op = xs + g * 25 * 64;
    for (int idx = threadIdx.x; idx < 25 * 64; idx += blockDim.x) {
        int j = idx >> 6, c = idx & 63;
        op[idx] = tile[c][j];
    }
}

__global__ void xt_kernel(const float* __restrict__ src, float* __restrict__ xt) {
    int g = blockIdx.x;             // b*25 + j
    int b = g / 25, j = g - b * 25;
    __shared__ float tile[64][65];  // [c][t]
    const float* sp = src + b * 102400 + j;
    for (int idx = threadIdx.x; idx < 64 * 64; idx += blockDim.x) {
        int c = idx >> 6, t = idx & 63;
        tile[c][t] = sp[c * 1600 + t * 25];
    }
    __syncthreads();
    float* op = xt + g * 64 * 64;
    for (int idx = threadIdx.x; idx < 64 * 64; idx += blockDim.x) {
        int t = idx >> 6, c = idx & 63;
        op[idx] = tile[c][t];
    }
}

// ---------------------------------------------------------------------------
// Score kernel: sc[g][q][n] = dot(x[g][n], w[q])  q = sd*4+h, GPB graphs/block.
// ---------------------------------------------------------------------------
template <int N, int GPB>
__global__ __launch_bounds__(256) void score_kernel(
    const float* __restrict__ x,   // (G,N,64)
    const float* __restrict__ w,   // [2][4][64]
    float* __restrict__ sc) {      // (G,8,N)
    constexpr int NP = GPB * N;
    constexpr int LD = NP + 1;
    __shared__ float xlT[64 * LD];
    __shared__ float wl[512];
    const int g0 = blockIdx.x * GPB;
    const int tid = threadIdx.x;
    const float* xp = x + (size_t)g0 * N * 64;
    for (int idx = tid; idx < NP * 64; idx += 256) {
        int n = idx >> 6, c = idx & 63;
        xlT[c * LD + n] = xp[idx];
    }
    for (int idx = tid; idx < 512; idx += 256) wl[idx] = w[idx];
    __syncthreads();
    float* op = sc + (size_t)g0 * 8 * N;
    for (int idx = tid; idx < 8 * NP; idx += 256) {
        int n = idx % N;
        int q = (idx / N) & 7;
        int gs = idx / (8 * N);
        int nn = gs * N + n;
        const float* wp = wl + q * 64;
        float acc = 0.f;
        #pragma unroll 8
        for (int c = 0; c < 64; ++c) acc += xlT[c * LD + nn] * wp[c];
        op[idx] = acc;
    }
}

// ---------------------------------------------------------------------------
// Diff-pool, register-tiled (unchanged from round 4).
// ---------------------------------------------------------------------------
template <int N, int K, int KP>
__global__ __launch_bounds__(256, 3) void pool_kernel(
    const float* __restrict__ x,    // (G,N,64)
    const float* __restrict__ W1T,  // (64,64) [c][d]
    const float* __restrict__ b1,   // (64)
    const float* __restrict__ W2T,  // (64,KP) [d][k], pad cols zero
    const float* __restrict__ b2,   // (K)
    float* __restrict__ xo) {       // (G,K,64)
    constexpr int NP = (N + 3) & ~3;
    constexpr int LDN = NP + 1;
    __shared__ float xlT[64 * LDN];  // [c][n]
    __shared__ float yT[64 * LDN];   // [d][n]
    __shared__ float sT[KP * LDN];   // [k][n]
    const int g = blockIdx.x, tid = threadIdx.x;
    const float* xp = x + (size_t)g * N * 64;
    for (int i4 = tid; i4 < N * 16; i4 += 256) {
        int n = i4 >> 4, c0 = (i4 & 15) << 2;
        float4 v = ((const float4*)xp)[i4];
        xlT[(c0 + 0) * LDN + n] = v.x;
        xlT[(c0 + 1) * LDN + n] = v.y;
        xlT[(c0 + 2) * LDN + n] = v.z;
        xlT[(c0 + 3) * LDN + n] = v.w;
    }
    if constexpr (NP > N) {
        for (int i = tid; i < 64 * (NP - N); i += 256) {
            int c = i / (NP - N), n = N + i % (NP - N);
            xlT[c * LDN + n] = 0.f;
        }
    }
    __syncthreads();
    constexpr int T1 = (NP / 4) * 16;
    if (tid < T1) {
        int d0 = (tid & 15) << 2, n0 = (tid >> 4) << 2;
        float acc[4][4] = {};
        #pragma unroll 4
        for (int c = 0; c < 64; ++c) {
            float4 w4 = *(const float4*)(W1T + c * 64 + d0);
            float wv[4] = {w4.x, w4.y, w4.z, w4.w};
            float xv[4];
            #pragma unroll
            for (int r = 0; r < 4; ++r) xv[r] = xlT[c * LDN + n0 + r];
            #pragma unroll
            for (int r = 0; r < 4; ++r)
                #pragma unroll
                for (int cc = 0; cc < 4; ++cc) acc[r][cc] += xv[r] * wv[cc];
        }
        float4 b4 = *(const float4*)(b1 + d0);
        float bb[4] = {b4.x, b4.y, b4.z, b4.w};
        #pragma unroll
        for (int r = 0; r < 4; ++r)
            #pragma unroll
            for (int cc = 0; cc < 4; ++cc)
                yT[(d0 + cc) * LDN + n0 + r] = fmaxf(acc[r][cc] + bb[cc], 0.f);
    }
    __syncthreads();
    constexpr int KG4 = KP / 4;
    constexpr int T2 = (NP / 4) * KG4;
    if (tid < T2) {
        int k0 = (tid % KG4) << 2, n0 = (tid / KG4) << 2;
        float acc[4][4] = {};
        #pragma unroll 4
        for (int d = 0; d < 64; ++d) {
            float4 w4 = *(const float4*)(W2T + d * KP + k0);
            float wv[4] = {w4.x, w4.y, w4.z, w4.w};
            float yv[4];
            #pragma unroll
            for (int r = 0; r < 4; ++r) yv[r] = yT[d * LDN + n0 + r];
            #pragma unroll
            for (int r = 0; r < 4; ++r)
                #pragma unroll
                for (int cc = 0; cc < 4; ++cc) acc[r][cc] += yv[r] * wv[cc];
        }
        #pragma unroll
        for (int cc = 0; cc < 4; ++cc) {
            int k = k0 + cc;
            float bb = (k < K) ? b2[k] : 0.f;
            #pragma unroll
            for (int r = 0; r < 4; ++r)
                sT[k * LDN + n0 + r] = (k < K) ? (acc[r][cc] + bb) : -1e30f;
        }
    }
    __syncthreads();
    if (tid < NP) {
        float m = -1e30f;
        #pragma unroll
        for (int k = 0; k < KP; ++k) m = fmaxf(m, sT[k * LDN + tid]);
        float sum = 0.f;
        float e[KP];
        #pragma unroll
        for (int k = 0; k < KP; ++k) { e[k] = __expf(sT[k * LDN + tid] - m); sum += e[k]; }
        float inv = 1.f / sum;
        #pragma unroll
        for (int k = 0; k < KP; ++k) sT[k * LDN + tid] = e[k] * inv;
    }
    __syncthreads();
    constexpr int KG2 = (K + 1) / 2;
    constexpr int T3 = KG2 * 16;
    if (tid < T3) {
        int k0 = (tid % KG2) * 2, c0 = (tid / KG2) * 4;
        float acc0[4] = {}, acc1[4] = {};
        #pragma unroll 4
        for (int n = 0; n < N; ++n) {
            float sv0 = sT[k0 * LDN + n];
            float sv1 = sT[(k0 + 1) * LDN + n];
            float xv[4];
            #pragma unroll
            for (int j = 0; j < 4; ++j) xv[j] = xlT[(c0 + j) * LDN + n];
            #pragma unroll
            for (int j = 0; j < 4; ++j) { acc0[j] += sv0 * xv[j]; acc1[j] += sv1 * xv[j]; }
        }
        float* op = xo + (size_t)g * K * 64;
        *(float4*)&op[k0 * 64 + c0] = make_float4(acc0[0], acc0[1], acc0[2], acc0[3]);
        if (k0 + 1 < K)
            *(float4*)&op[(k0 + 1) * 64 + c0] = make_float4(acc1[0], acc1[1], acc1[2], acc1[3]);
    }
}

// ---------------------------------------------------------------------------
// Fused GAT0 + low-rank fuse, temporal. Score-only inputs; A1/A2 built in LDS.
// Block = (g,h) XCD-swizzled, 256 threads, 4x4 register tile, ~18KB LDS.
// ---------------------------------------------------------------------------
__global__ __launch_bounds__(256, 8) void gatfuse_t(
    const float* __restrict__ sc0,  // (1600,8,64)
    const float* __restrict__ sc1,  // (1600,8,32)
    const float* __restrict__ sc2,  // (1600,8,12)
    const float* __restrict__ L1,   // (4,64,32)
    const float* __restrict__ R1,   // (4,32,64)
    const float* __restrict__ L2,   // (4,64,12)
    const float* __restrict__ R2,   // (4,12,64)
    float* __restrict__ out)        // (1600,4,64,64)
{
    const int bid = blockIdx.x;
    const int g = (bid & 7) | ((bid >> 5) << 3);   // 4 heads of one g -> same XCD
    const int h = (bid >> 3) & 3;
    const int tid = threadIdx.x;
    __shared__ float t1T[32 * 64];   // [l][j]
    __shared__ float t2T[12 * 64];   // [l][j]
    __shared__ float A1[32 * 36];    // [k][l], pad 36 (conflict-free + aligned)
    __shared__ float A2[12 * 13];    // [k][l]
    __shared__ float a01[64], a02[64], mj0[64], iv0[64];
    __shared__ float a11[32], a12[32], mj1[32], iv1[32];
    __shared__ float a21[12], a22[12], mj2[12], iv2[12];

    // ---- stage scores
    if (tid < 128) {
        int t = tid & 63, sd = tid >> 6;
        (sd ? a02 : a01)[t] = sc0[((size_t)g * 8 + sd * 4 + h) * 64 + t];
    } else if (tid < 192) {
        int u = tid - 128, sd = u >> 5, n = u & 31;
        (sd ? a12 : a11)[n] = sc1[((size_t)g * 8 + sd * 4 + h) * 32 + n];
    } else if (tid < 216) {
        int u = tid - 192, sd = u / 12, n = u - sd * 12;
        (sd ? a22 : a21)[n] = sc2[((size_t)g * 8 + sd * 4 + h) * 12 + n];
    }
    __syncthreads();

    // ---- softmax column stats, all levels (leaky monotonic -> exact max)
    if (tid < 64) {
        float mx = a02[0];
        for (int i = 1; i < 64; ++i) mx = fmaxf(mx, a02[i]);
        float aj = a01[tid];
        float mj = leaky(aj + mx);
        float s = 0.f;
        for (int i = 0; i < 64; ++i) s += __expf(leaky(aj + a02[i]) - mj);
        mj0[tid] = mj; iv0[tid] = 1.f / s;
    } else if (tid < 96) {
        int l = tid - 64;
        float mx = a12[0];
        for (int k = 1; k < 32; ++k) mx = fmaxf(mx, a12[k]);
        float aj = a11[l];
        float mj = leaky(aj + mx);
        float s = 0.f;
        for (int k = 0; k < 32; ++k) s += __expf(leaky(aj + a12[k]) - mj);
        mj1[l] = mj; iv1[l] = 1.f / s;
    } else if (tid < 108) {
        int l = tid - 96;
        float mx = a22[0];
        for (int k = 1; k < 12; ++k) mx = fmaxf(mx, a22[k]);
        float aj = a21[l];
        float mj = leaky(aj + mx);
        float s = 0.f;
        for (int k = 0; k < 12; ++k) s += __expf(leaky(aj + a22[k]) - mj);
        mj2[l] = mj; iv2[l] = 1.f / s;
    }
    __syncthreads();

    // ---- build A1 (32x32), A2 (12x12) in LDS
    #pragma unroll
    for (int q = 0; q < 4; ++q) {
        int idx = q * 256 + tid;
        int k = idx >> 5, l = idx & 31;
        float e = leaky(a11[l] + a12[k]);
        A1[k * 36 + l] = __expf(e - mj1[l]) * iv1[l];
    }
    if (tid < 144) {
        int k = tid / 12, l = tid - k * 12;
        float e = leaky(a21[l] + a22[k]);
        A2[k * 13 + l] = __expf(e - mj2[l]) * iv2[l];
    }
    __syncthreads();

    // ---- t1T[l][j] = sum_k L1[j][k]*A1[k][l] : thread (j, 8 l's), acc8 regs
    {
        const int j = tid & 63, l0 = (tid >> 6) * 8;
        const float* ljrow = L1 + ((size_t)h * 64 + j) * 32;
        float acc8[8] = {};
        for (int k = 0; k < 32; ++k) {
            float lk = ljrow[k];
            float4 a4a = *(const float4*)&A1[k * 36 + l0];
            float4 a4b = *(const float4*)&A1[k * 36 + l0 + 4];
            acc8[0] += lk * a4a.x; acc8[1] += lk * a4a.y;
            acc8[2] += lk * a4a.z; acc8[3] += lk * a4a.w;
            acc8[4] += lk * a4b.x; acc8[5] += lk * a4b.y;
            acc8[6] += lk * a4b.z; acc8[7] += lk * a4b.w;
        }
        #pragma unroll
        for (int lo = 0; lo < 8; ++lo) t1T[(l0 + lo) * 64 + j] = acc8[lo];
        // t2T: 3 l's per thread
        const int lb = (tid >> 6) * 3;
        float lj2[12];
        const float4* lp2 = (const float4*)(L2 + ((size_t)h * 64 + j) * 12);
        #pragma unroll
        for (int q = 0; q < 3; ++q) {
            float4 v = lp2[q];
            lj2[q * 4] = v.x; lj2[q * 4 + 1] = v.y;
            lj2[q * 4 + 2] = v.z; lj2[q * 4 + 3] = v.w;
        }
        #pragma unroll
        for (int lo = 0; lo < 3; ++lo) {
            int l = lb + lo;
            float acc = 0.f;
            #pragma unroll
            for (int k = 0; k < 12; ++k) acc += lj2[k] * A2[k * 13 + l];
            t2T[l * 64 + j] = acc;
        }
    }
    __syncthreads();

    // ---- main 4x4 register-tiled output
    const int i0 = (tid >> 4) << 2, m0 = (tid & 15) << 2;
    float acc[4][4];
    {
        float4 q1 = *(const float4*)&a01[m0];
        float4 qm = *(const float4*)&mj0[m0];
        float4 qv = *(const float4*)&iv0[m0];
        float4 q2 = *(const float4*)&a02[i0];
        float am[4] = {q1.x, q1.y, q1.z, q1.w};
        float mv[4] = {qm.x, qm.y, qm.z, qm.w};
        float iv[4] = {qv.x, qv.y, qv.z, qv.w};
        float ai[4] = {q2.x, q2.y, q2.z, q2.w};
        #pragma unroll
        for (int r = 0; r < 4; ++r)
            #pragma unroll
            for (int c = 0; c < 4; ++c) {
                float e = am[c] + ai[r];
                e = e >= 0.f ? e : 0.2f * e;
                acc[r][c] = __expf(e - mv[c]) * iv[c];
            }
    }
    const float* r1b = R1 + (size_t)h * 2048;
    #pragma unroll 8
    for (int l = 0; l < 32; ++l) {
        float4 t4 = *(const float4*)&t1T[l * 64 + i0];
        float4 r4 = *(const float4*)(r1b + l * 64 + m0);
        float tv[4] = {t4.x, t4.y, t4.z, t4.w};
        float rv[4] = {r4.x, r4.y, r4.z, r4.w};
        #pragma unroll
        for (int r = 0; r < 4; ++r)
            #pragma unroll
            for (int c = 0; c < 4; ++c) acc[r][c] += tv[r] * rv[c];
    }
    const float* r2b = R2 + (size_t)h * 768;
    #pragma unroll 4
    for (int l = 0; l < 12; ++l) {
        float4 t4 = *(const float4*)&t2T[l * 64 + i0];
        float4 r4 = *(const float4*)(r2b + l * 64 + m0);
        float tv[4] = {t4.x, t4.y, t4.z, t4.w};
        float rv[4] = {r4.x, r4.y, r4.z, r4.w};
        #pragma unroll
        for (int r = 0; r < 4; ++r)
            #pragma unroll
            for (int c = 0; c < 4; ++c) acc[r][c] += tv[r] * rv[c];
    }
    float* op = out + ((size_t)g * 4 + h) * 4096;
    #pragma unroll
    for (int r = 0; r < 4; ++r)
        *(float4*)&op[(i0 + r) * 64 + m0] =
            make_float4(acc[r][0], acc[r][1], acc[r][2], acc[r][3]);
}

// ---------------------------------------------------------------------------
// Fused GAT0 + fuse, spatial. Score-only inputs; padded zero-filled tiles so
// the output dot is pure float4 LDS reads. Block = g, head = tid>>6.
// ---------------------------------------------------------------------------
__global__ __launch_bounds__(256, 6) void gatfuse_s(
    const float* __restrict__ sc0,  // (4096,8,25)
    const float* __restrict__ sc1,  // (4096,8,12)
    const float* __restrict__ sc2,  // (4096,8,5)
    const float* __restrict__ L1,   // (4,25,12)
    const float* __restrict__ R1,   // (4,12,25)
    const float* __restrict__ L2,   // (4,25,5)
    const float* __restrict__ R2,   // (4,5,25)
    float* __restrict__ out)        // (4096,4,25,25)
{
    const int g = blockIdx.x;
    const int tid = threadIdx.x;
    const int h = tid >> 6, t = tid & 63;
    __shared__ float A1[4][12 * 13];   // [k][l]
    __shared__ float A2[4][5 * 6];     // [k][l]
    __shared__ float t1l[4][25 * 16];  // [i][l], pad zero l>=12
    __shared__ float t2l[4][25 * 8];   // [i][l], pad zero l>=5
    __shared__ float r1T[4][25 * 16];  // [m][l], pad zero l>=12
    __shared__ float r2T[4][25 * 8];   // [m][l], pad zero l>=5
    __shared__ float a01[4][25], a02[4][25], mj0[4][25], iv0[4][25];
    __shared__ float a11[4][12], a12[4][12], mj1[4][12], iv1[4][12];
    __shared__ float a21[4][5], a22[4][5], mj2[4][5], iv2[4][5];

    // ---- stage scores + R (transposed, zero-padded)
    if (t < 50) {
        int sd = t / 25, n = t - sd * 25;
        (sd ? a02[h] : a01[h])[n] = sc0[((size_t)g * 8 + sd * 4 + h) * 25 + n];
    }
    if (t < 24) {
        int sd = t / 12, n = t - sd * 12;
        (sd ? a12[h] : a11[h])[n] = sc1[((size_t)g * 8 + sd * 4 + h) * 12 + n];
    }
    if (t < 10) {
        int sd = t / 5, n = t - sd * 5;
        (sd ? a22[h] : a21[h])[n] = sc2[((size_t)g * 8 + sd * 4 + h) * 5 + n];
    }
    for (int idx = t; idx < 400; idx += 64) {
        int m = idx >> 4, l = idx & 15;
        r1T[h][idx] = (l < 12) ? R1[h * 300 + l * 25 + m] : 0.f;
    }
    for (int idx = t; idx < 200; idx += 64) {
        int m = idx >> 3, l = idx & 7;
        r2T[h][idx] = (l < 5) ? R2[h * 125 + l * 25 + m] : 0.f;
    }
    __syncthreads();

    // ---- stats
    if (t < 25) {
        float mx = a02[h][0];
        for (int i = 1; i < 25; ++i) mx = fmaxf(mx, a02[h][i]);
        float aj = a01[h][t];
        float mj = leaky(aj + mx);
        float s = 0.f;
        for (int i = 0; i < 25; ++i) s += __expf(leaky(aj + a02[h][i]) - mj);
        mj0[h][t] = mj; iv0[h][t] = 1.f / s;
    }
    if (t >= 32 && t < 44) {
        int l = t - 32;
        float mx = a12[h][0];
        for (int k = 1; k < 12; ++k) mx = fmaxf(mx, a12[h][k]);
        float aj = a11[h][l];
        float mj = leaky(aj + mx);
        float s = 0.f;
        for (int k = 0; k < 12; ++k) s += __expf(leaky(aj + a12[h][k]) - mj);
        mj1[h][l] = mj; iv1[h][l] = 1.f / s;
    }
    if (t >= 48 && t < 53) {
        int l = t - 48;
        float mx = a22[h][0];
        for (int k = 1; k < 5; ++k) mx = fmaxf(mx, a22[h][k]);
        float aj = a21[h][l];
        float mj = leaky(aj + mx);
        float s = 0.f;
        for (int k = 0; k < 5; ++k) s += __expf(leaky(aj + a22[h][k]) - mj);
        mj2[h][l] = mj; iv2[h][l] = 1.f / s;
    }
    __syncthreads();

    // ---- build A1 (12x12), A2 (5x5)
    for (int idx = t; idx < 144; idx += 64) {
        int k = idx / 12, l = idx - k * 12;
        float e = leaky(a11[h][l] + a12[h][k]);
        A1[h][k * 13 + l] = __expf(e - mj1[h][l]) * iv1[h][l];
    }
    if (t < 25) {
        int k = t / 5, l = t - (t / 5) * 5;
        float e = leaky(a21[h][l] + a22[h][k]);
        A2[h][k * 6 + l] = __expf(e - mj2[h][l]) * iv2[h][l];
    }
    __syncthreads();

    // ---- t1l[i][l] = sum_k L1[i][k] A1[k][l]; t2l likewise (zero-padded)
    if (t < 25) {
        float lj[12];
        const float4* lp = (const float4*)(L1 + ((size_t)h * 25 + t) * 12);
        #pragma unroll
        for (int q = 0; q < 3; ++q) {
            float4 v = lp[q];
            lj[q * 4] = v.x; lj[q * 4 + 1] = v.y; lj[q * 4 + 2] = v.z; lj[q * 4 + 3] = v.w;
        }
        #pragma unroll
        for (int l = 0; l < 12; ++l) {
            float acc = 0.f;
            #pragma unroll
            for (int k = 0; k < 12; ++k) acc += lj[k] * A1[h][k * 13 + l];
            t1l[h][t * 16 + l] = acc;
        }
        #pragma unroll
        for (int l = 12; l < 16; ++l) t1l[h][t * 16 + l] = 0.f;
        float lj2[5];
        const float* lp2 = L2 + ((size_t)h * 25 + t) * 5;
        #pragma unroll
        for (int k = 0; k < 5; ++k) lj2[k] = lp2[k];
        #pragma unroll
        for (int l = 0; l < 5; ++l) {
            float acc = 0.f;
            #pragma unroll
            for (int k = 0; k < 5; ++k) acc += lj2[k] * A2[h][k * 6 + l];
            t2l[h][t * 8 + l] = acc;
        }
        #pragma unroll
        for (int l = 5; l < 8; ++l) t2l[h][t * 8 + l] = 0.f;
    }
    __syncthreads();

    // ---- output: 625 per head, vector LDS dots (pads are zero)
    float* op = out + ((size_t)g * 4 + h) * 625;
    for (int idx = t; idx < 625; idx += 64) {
        int i = idx / 25, m = idx - i * 25;
        float e = a01[h][m] + a02[h][i];
        e = e >= 0.f ? e : 0.2f * e;
        float val = __expf(e - mj0[h][m]) * iv0[h][m];
        const float* t1r = &t1l[h][i * 16];
        const float* r1c = &r1T[h][m * 16];
        #pragma unroll
        for (int q = 0; q < 4; ++q) {
            float4 tv = *(const float4*)&t1r[q * 4];
            float4 rv = *(const float4*)&r1c[q * 4];
            val += tv.x * rv.x + tv.y * rv.y + tv.z * rv.z + tv.w * rv.w;
        }
        const float* t2r = &t2l[h][i * 8];
        const float* r2c = &r2T[h][m * 8];
        #pragma unroll
        for (int q = 0; q < 2; ++q) {
            float4 tv = *(const float4*)&t2r[q * 4];
            float4 rv = *(const float4*)&r2c[q * 4];
            val += tv.x * rv.x + tv.y * rv.y + tv.z * rv.z + tv.w * rv.w;
        }
        op[idx] = val;
    }
}

// ---------------------------------------------------------------------------
extern "C" void kernel_launch(void* const* d_in, const int* in_sizes, int n_in,
                              void* d_out, int out_size, void* d_ws, size_t ws_size,
                              hipStream_t stream) {
    const float* src    = (const float*)d_in[0];
    const float* lin    = (const float*)d_in[1];
    const float* asrc   = (const float*)d_in[2];
    const float* adst   = (const float*)d_in[3];
    const float* sp0_W1 = (const float*)d_in[4];
    const float* sp0_b1 = (const float*)d_in[5];
    const float* sp0_W2 = (const float*)d_in[6];
    const float* sp0_b2 = (const float*)d_in[7];
    const float* sp1_W1 = (const float*)d_in[8];
    const float* sp1_b1 = (const float*)d_in[9];
    const float* sp1_W2 = (const float*)d_in[10];
    const float* sp1_b2 = (const float*)d_in[11];
    const float* tp0_W1 = (const float*)d_in[12];
    const float* tp0_b1 = (const float*)d_in[13];
    const float* tp0_W2 = (const float*)d_in[14];
    const float* tp0_b2 = (const float*)d_in[15];
    const float* tp1_W1 = (const float*)d_in[16];
    const float* tp1_b1 = (const float*)d_in[17];
    const float* tp1_W2 = (const float*)d_in[18];
    const float* tp1_b2 = (const float*)d_in[19];
    const float* sl0    = (const float*)d_in[20];
    const float* sr0    = (const float*)d_in[21];
    const float* sl1    = (const float*)d_in[22];
    const float* sr1    = (const float*)d_in[23];
    const float* tl0    = (const float*)d_in[24];
    const float* tr0    = (const float*)d_in[25];
    const float* tl1    = (const float*)d_in[26];
    const float* tr1    = (const float*)d_in[27];

    float* out_s = (float*)d_out;                 // (4096,4,25,25)
    float* out_t = out_s + 10240000;              // (1600,4,64,64)

    float* ws   = (float*)d_ws;
    float* wbuf = ws;                             // 3072 used (reserve 4096)
    float* wT   = ws + 4096;                      // 20480
    float* base = ws + 24576;

    float* sp0_W1T = wT;
    float* sp1_W1T = wT + 4096;
    float* tp0_W1T = wT + 8192;
    float* tp1_W1T = wT + 12288;
    float* sp0_W2T = wT + 16384;
    float* sp1_W2T = wT + 17152;
    float* tp0_W2T = wT + 17664;
    float* tp1_W2T = wT + 19712;

    // x region (spatial/temporal aliased; branches sequential)
    float* xs  = base;                            // 4096*25*64 = 6,553,600
    float* xs1 = base + 6553600;                  // 4096*12*64 = 3,145,728
    float* xs2 = base + 9699328;                  // 4096*5*64  = 1,310,720
    float* xt  = base;                            // 1600*64*64 = 6,553,600
    float* xt1 = base + 6553600;                  // 1600*32*64 = 3,276,800
    float* xt2 = base + 9830400;                  // 1600*12*64 = 1,228,800
    float* scb = base + 11059200;                 // score region (aliased)
    float* scS0 = scb;                            // 4096*8*25 = 819,200
    float* scS1 = scb + 819200;                   // 4096*8*12 = 393,216
    float* scS2 = scb + 1212416;                  // 4096*8*5  = 163,840
    float* scT0 = scb;                            // 1600*8*64 = 819,200
    float* scT1 = scb + 819200;                   // 1600*8*32 = 409,600
    float* scT2 = scb + 1228800;                  // 1600*8*12 = 153,600

    wprep_kernel<<<6, 256, 0, stream>>>(lin, asrc, adst, wbuf);
    wtrans_kernel<<<80, 256, 0, stream>>>(sp0_W1, sp1_W1, tp0_W1, tp1_W1,
                                          sp0_W2, sp1_W2, tp0_W2, tp1_W2, wT);

    // ---- spatial branch ----
    xs_kernel<<<4096, 256, 0, stream>>>(src, xs);
    score_kernel<25, 2><<<2048, 256, 0, stream>>>(xs, wbuf + 0 * 512, scS0);
    pool_kernel<25, 12, 12><<<4096, 256, 0, stream>>>(xs, sp0_W1T, sp0_b1, sp0_W2T, sp0_b2, xs1);
    score_kernel<12, 4><<<1024, 256, 0, stream>>>(xs1, wbuf + 1 * 512, scS1);
    pool_kernel<12, 5, 8><<<4096, 256, 0, stream>>>(xs1, sp1_W1T, sp1_b1, sp1_W2T, sp1_b2, xs2);
    score_kernel<5, 8><<<512, 256, 0, stream>>>(xs2, wbuf + 2 * 512, scS2);
    gatfuse_s<<<4096, 256, 0, stream>>>(scS0, scS1, scS2, sl0, sr0, sl1, sr1, out_s);

    // ---- temporal branch ----
    xt_kernel<<<1600, 256, 0, stream>>>(src, xt);
    score_kernel<64, 1><<<1600, 256, 0, stream>>>(xt, wbuf + 3 * 512, scT0);
    pool_kernel<64, 32, 32><<<1600, 256, 0, stream>>>(xt, tp0_W1T, tp0_b1, tp0_W2T, tp0_b2, xt1);
    score_kernel<32, 2><<<800, 256, 0, stream>>>(xt1, wbuf + 4 * 512, scT1);
    pool_kernel<32, 12, 12><<<1600, 256, 0, stream>>>(xt1, tp1_W1T, tp1_b1, tp1_W2T, tp1_b2, xt2);
    score_kernel<12, 4><<<400, 256, 0, stream>>>(xt2, wbuf + 5 * 512, scT2);
    gatfuse_t<<<6400, 256, 0, stream>>>(scT0, scT1, scT2, tl0, tr0, tl1, tr1, out_t);
}